// Round 11
// baseline (195.809 us; speedup 1.0000x reference)
//
#include <hip/hip_runtime.h>

#define S_LEN 4096
#define B_SZ 8
#define KTOT 384            // M (256) + D (128)
#define CPROWS 544          // 8-elem rows per parity copy (fallback path)
#define HN_OFF 8388608      // 8*4096*256

typedef __attribute__((ext_vector_type(8))) short short8;
typedef __attribute__((ext_vector_type(4))) float f32x4;

typedef const __attribute__((address_space(1))) unsigned int as1_u32;
typedef __attribute__((address_space(3))) unsigned int as3_u32;

__device__ __forceinline__ void gload16(const short* g, short* l) {
  __builtin_amdgcn_global_load_lds((as1_u32*)g, (as3_u32*)l, 16, 0, 0);
}

__device__ __forceinline__ short f2bf(float f) {
  union { float f; unsigned u; } v; v.f = f;
  unsigned r = v.u + 0x7FFFu + ((v.u >> 16) & 1u);
  return (short)(r >> 16);
}

__device__ __forceinline__ float2 cmulf(float2 a, float2 b) {
  return make_float2(a.x * b.x - a.y * b.y, a.x * b.y + a.y * b.x);
}
__device__ __forceinline__ float2 f2add(float2 a, float2 b) { return make_float2(a.x + b.x, a.y + b.y); }
__device__ __forceinline__ float2 f2sub(float2 a, float2 b) { return make_float2(a.x - b.x, a.y - b.y); }

// LDS physical index swizzle: breaks the 4-stride bank pattern of radix-4 writes.
#define IDX(i) ((i) + ((i) >> 5))
#define FFT_LDS 8448        // 8192 + 256 pad

// In-place (regs+barrier) Stockham DIF FFT, n=8192 = 4^6 * 2.
// Pass pi: n_cur = 8192>>(2pi), s = 1<<(2pi); butterflies read at
// {g, g+2048, g+4096, g+6144}, write at 4g-3q + k*s; w1 = Wt[g-q].
__device__ void fft8192(float2* __restrict__ buf, const float2* __restrict__ Wt, int tid) {
  #pragma unroll
  for (int pi = 0; pi < 6; ++pi) {
    const int s = 1 << (2 * pi);
    float2 o[8][4];
    int wb[8];
    #pragma unroll
    for (int i = 0; i < 8; ++i) {
      int g = i * 256 + tid;
      int qq = g & (s - 1);
      float2 A = buf[IDX(g)], B = buf[IDX(g + 2048)], C = buf[IDX(g + 4096)], D = buf[IDX(g + 6144)];
      float2 w1 = Wt[g - qq];
      float2 w2 = cmulf(w1, w1), w3 = cmulf(w2, w1);
      float2 apc = f2add(A, C), amc = f2sub(A, C), bpd = f2add(B, D), bmd = f2sub(B, D);
      o[i][0] = f2add(apc, bpd);
      o[i][1] = cmulf(make_float2(amc.x + bmd.y, amc.y - bmd.x), w1);
      o[i][2] = cmulf(f2sub(apc, bpd), w2);
      o[i][3] = cmulf(make_float2(amc.x - bmd.y, amc.y + bmd.x), w3);
      wb[i] = 4 * g - 3 * qq;
    }
    __syncthreads();
    #pragma unroll
    for (int i = 0; i < 8; ++i)
      #pragma unroll
      for (int k2 = 0; k2 < 4; ++k2)
        buf[IDX(wb[i] + k2 * s)] = o[i][k2];
    __syncthreads();
  }
  // final radix-2 (n=2, s=4096): twiddle = 1
  float2 ea[16], eb[16];
  #pragma unroll
  for (int i = 0; i < 16; ++i) {
    int q2 = i * 256 + tid;
    ea[i] = buf[IDX(q2)];
    eb[i] = buf[IDX(q2 + 4096)];
  }
  __syncthreads();
  #pragma unroll
  for (int i = 0; i < 16; ++i) {
    int q2 = i * 256 + tid;
    buf[IDX(q2)]        = f2add(ea[i], eb[i]);
    buf[IDX(q2 + 4096)] = f2sub(ea[i], eb[i]);
  }
  __syncthreads();
}

// K1 fused prep (round-10 + plain u write for the FFT path):
__global__ __launch_bounds__(256) void k_prep(const float* __restrict__ x,
                                              const float* __restrict__ Wu,
                                              const float* __restrict__ bu,
                                              const float* __restrict__ H,
                                              const float* __restrict__ Wh,
                                              short* __restrict__ mx,
                                              short* __restrict__ cp,
                                              short* __restrict__ Hb,
                                              short* __restrict__ wht,
                                              float* __restrict__ u) {
  int bx = blockIdx.x;
  if (bx >= 12360) {
    int j = (bx - 12360) * 256 + threadIdx.x;
    if (j < 256 * KTOT) {
      int n = j / KTOT, k = j % KTOT;
      wht[j] = f2bf(Wh[k * 256 + n]);
    }
    return;
  }
  if (bx >= 8264) {
    int i = (bx - 8264) * 256 + threadIdx.x;
    Hb[i] = f2bf(H[i]);
    return;
  }
  if (bx >= 8192) {
    int idx = (bx - 8192) * 256 + threadIdx.x;
    if (idx < 18432) {
      int j = idx & 7;
      int r = 508 + ((idx >> 3) % 36);
      int rem = (idx >> 3) / 36;
      int p = rem & 7;
      int b = rem >> 3;
      int e = 8 * r + p + j;
      if (e >= S_LEN)
        cp[((size_t)(b * 8 + p) * CPROWS + r) * 8 + j] = 0;
    }
    return;
  }
  int row = bx * 4 + (threadIdx.x >> 6);   // b*4096 + t
  int l = threadIdx.x & 63;
  const float* xr = x + (size_t)row * 128;
  float x0 = xr[l], x1 = xr[l + 64];
  float s = x0 * Wu[l] + x1 * Wu[l + 64];
  #pragma unroll
  for (int m = 32; m >= 1; m >>= 1) s += __shfl_xor(s, m, 64);
  short* mrow = mx + (size_t)row * KTOT + 256;
  mrow[l]      = f2bf(x0);
  mrow[l + 64] = f2bf(x1);
  float v = s + bu[0];
  v = v > 0.0f ? v : 0.0f;
  short vb = f2bf(v);
  if (l == 8) u[row] = v;
  if (l < 8) {
    int t = row & (S_LEN - 1);
    int b = row >> 12;
    int e = (S_LEN - 1) - t;
    int p = l;
    if (e >= p) {
      int d = e - p;
      cp[((size_t)(b * 8 + p) * CPROWS + (d >> 3)) * 8 + (d & 7)] = vb;
    }
  }
}

// Twiddle table W[j] = exp(-2*pi*i*j/8192), double-precision angles.
__global__ __launch_bounds__(256) void k_twid(float2* __restrict__ Wt) {
  int j = blockIdx.x * 256 + threadIdx.x;
  double th = (double)j * 7.66990393942820614e-4;   // 2*pi/8192
  Wt[j] = make_float2((float)cos(th), (float)-sin(th));
}

// Forward FFT of zero-padded real rows: r<256 -> H row r; else u row (r-256).
__global__ __launch_bounds__(256) void k_fft(const float* __restrict__ H,
                                             const float* __restrict__ u,
                                             const float2* __restrict__ Wt,
                                             float2* __restrict__ fftH,
                                             float2* __restrict__ fftU) {
  __shared__ float2 buf[FFT_LDS];
  int r = blockIdx.x;
  int tid = threadIdx.x;
  const float* src = (r < 256) ? (H + (size_t)r * 4096) : (u + (size_t)(r - 256) * 4096);
  #pragma unroll
  for (int i = 0; i < 16; ++i) {
    int idx = i * 256 + tid;
    buf[IDX(idx)] = make_float2(src[idx], 0.0f);
  }
  #pragma unroll
  for (int i = 16; i < 32; ++i)
    buf[IDX(i * 256 + tid)] = make_float2(0.0f, 0.0f);
  __syncthreads();
  fft8192(buf, Wt, tid);
  float2* dst = (r < 256) ? (fftH + (size_t)r * 8192) : (fftU + (size_t)(r - 256) * 8192);
  #pragma unroll
  for (int i = 0; i < 32; ++i) {
    int idx = i * 256 + tid;
    dst[idx] = buf[IDX(idx)];
  }
}

// Inverse: m[b][:,q] = Re(FFT(conj(fftU[b]*fftH[q])))/8192, first 4096 samples,
// written coalesced as bf16 into mcol[b][q][s].
__global__ __launch_bounds__(256) void k_ifft(const float2* __restrict__ fftU,
                                              const float2* __restrict__ fftH,
                                              const float2* __restrict__ Wt,
                                              short* __restrict__ mcol) {
  __shared__ float2 buf[FFT_LDS];
  int bx = blockIdx.x;
  int b = bx >> 8, q = bx & 255;
  int tid = threadIdx.x;
  const float2* urow = fftU + (size_t)b * 8192;
  const float2* hrow = fftH + (size_t)q * 8192;
  #pragma unroll
  for (int i = 0; i < 32; ++i) {
    int idx = i * 256 + tid;
    float2 uu = urow[idx], hh = hrow[idx];
    buf[IDX(idx)] = make_float2(uu.x * hh.x - uu.y * hh.y,
                                -(uu.x * hh.y + uu.y * hh.x));
  }
  __syncthreads();
  fft8192(buf, Wt, tid);
  const float inv = 1.0f / 8192.0f;
  short* dst = mcol + ((size_t)(b * 256 + q)) * 4096;
  #pragma unroll
  for (int i = 0; i < 16; ++i) {
    int s2 = i * 256 + tid;
    dst[s2] = f2bf(buf[IDX(s2)].x * inv);
  }
}

// Transpose mcol[b][q][s] -> mx[(b*4096+s)*384 + q], 64x64 bf16 tiles.
__global__ __launch_bounds__(256) void k_tr(const short* __restrict__ mcol,
                                            short* __restrict__ mx) {
  __shared__ short tile[64][72];
  int bx = blockIdx.x;                 // 2048 = b(8) * st(16... 64) * qt(4)
  int b = bx >> 8, rem = bx & 255;
  int st = rem >> 2, qt = rem & 3;
  int s0 = st << 6, q0 = qt << 6;
  int tid = threadIdx.x;
  int r = tid >> 2, c = (tid & 3) << 4;
  const short* src = mcol + ((size_t)(b * 256 + q0 + r)) * 4096 + s0 + c;
  *(short8*)&tile[r][c]     = *(const short8*)src;
  *(short8*)&tile[r][c + 8] = *(const short8*)(src + 8);
  __syncthreads();
  int s = tid >> 2, qc = (tid & 3) << 4;
  short8 o0, o1;
  #pragma unroll
  for (int j = 0; j < 8; ++j) {
    o0[j] = tile[qc + j][s];
    o1[j] = tile[qc + 8 + j][s];
  }
  short* dst = mx + ((size_t)(b * S_LEN + s0 + s)) * KTOT + q0 + qc;
  *(short8*)dst       = o0;
  *(short8*)(dst + 8) = o1;
}

// ---- Fallback conv (round-10, known 52us) ----
__global__ __launch_bounds__(256) void k_conv(const short* __restrict__ cp,
                                              const short* __restrict__ Hb,
                                              short* __restrict__ mx) {
  __shared__ __attribute__((aligned(16))) short Bt[4][128 * 64];
  __shared__ __attribute__((aligned(16))) short Aw[4][2048];

  int i = blockIdx.x;
  int j  = i >> 1, lo = i & 1;
  int jj = j & 127;
  int fj = (j >> 7) ? (31 - (jj >> 3)) : (jj >> 3);
  int st = lo ? (31 - fj) : fj;
  int qt = lo;
  int b  = j & 7;
  int s0 = st << 7, q0 = qt << 7;

  int tid = threadIdx.x;
  int lane = tid & 63, wid = tid >> 6;
  int wr = wid >> 1, wc = wid & 1;
  int lm = lane & 15, kg = lane >> 4;
  int l3 = lane >> 3, l7 = lane & 7;
  int lm7 = lm & 7;

  int asbase = 496 - 16 * st;
  const short* bSrc = Hb + (size_t)(q0 + wid * 32 + l3) * S_LEN + ((l7 ^ l3) << 3);
  const short* aSrc = cp + ((size_t)(b * 8 + (l7 ^ l3)) * CPROWS + asbase + wid * 8 + l3) * 8;

  int dbase = 127 - 64 * wr - lm + 8 * kg;
  int aof[6];
  #pragma unroll
  for (int ii = 0; ii < 6; ++ii) {
    int d = (ii < 4) ? (dbase - 16 * ii) : (dbase + 96 - 16 * ii);
    aof[ii] = ((d & ~7) | ((d & 7) ^ ((d >> 3) & 7))) << 3;
  }
  int bRow = (wc * 64 + lm) * 64;
  int bof[8];
  #pragma unroll
  for (int nf = 0; nf < 4; ++nf)
    #pragma unroll
    for (int ks = 0; ks < 2; ++ks)
      bof[nf * 2 + ks] = bRow + nf * 1024 + (((ks << 5) + (kg << 3)) ^ (lm7 << 3));

  f32x4 acc[4][4];
  #pragma unroll
  for (int ii = 0; ii < 4; ++ii)
    #pragma unroll
    for (int jn = 0; jn < 4; ++jn)
      acc[ii][jn] = (f32x4){0.0f, 0.0f, 0.0f, 0.0f};

  int nchunks = 2 * st + 2;

  auto STAGE = [&](int cc) {
    int slot = cc & 3;
    #pragma unroll
    for (int ii = 0; ii < 4; ++ii)
      gload16(bSrc + (size_t)ii * 8 * S_LEN + cc * 64, &Bt[slot][(wid * 32 + ii * 8) * 64]);
    gload16(aSrc + cc * 64, &Aw[slot][wid * 512]);
  };

  STAGE(0);
  STAGE(1);

  for (int c = 0; c < nchunks; ++c) {
    if (c + 2 < nchunks) {
      STAGE(c + 2);
      asm volatile("s_waitcnt vmcnt(10) lgkmcnt(0)\n\ts_barrier" ::: "memory");
    } else if (c + 1 < nchunks) {
      asm volatile("s_waitcnt vmcnt(5) lgkmcnt(0)\n\ts_barrier" ::: "memory");
    } else {
      asm volatile("s_waitcnt vmcnt(0) lgkmcnt(0)\n\ts_barrier" ::: "memory");
    }
    const short* AwB = &Aw[c & 3][0];
    const short* BtB = &Bt[c & 3][0];
    short8 A[6];
    #pragma unroll
    for (int ii = 0; ii < 6; ++ii) A[ii] = *(const short8*)(AwB + aof[ii]);
    short8 Bf[8];
    #pragma unroll
    for (int ii = 0; ii < 8; ++ii) Bf[ii] = *(const short8*)(BtB + bof[ii]);
    __builtin_amdgcn_s_setprio(1);
    #pragma unroll
    for (int nf = 0; nf < 4; ++nf) {
      acc[0][nf] = __builtin_amdgcn_mfma_f32_16x16x32_bf16(A[0], Bf[nf * 2], acc[0][nf], 0, 0, 0);
      acc[1][nf] = __builtin_amdgcn_mfma_f32_16x16x32_bf16(A[1], Bf[nf * 2], acc[1][nf], 0, 0, 0);
      acc[2][nf] = __builtin_amdgcn_mfma_f32_16x16x32_bf16(A[2], Bf[nf * 2], acc[2][nf], 0, 0, 0);
      acc[3][nf] = __builtin_amdgcn_mfma_f32_16x16x32_bf16(A[3], Bf[nf * 2], acc[3][nf], 0, 0, 0);
    }
    #pragma unroll
    for (int nf = 0; nf < 4; ++nf) {
      acc[0][nf] = __builtin_amdgcn_mfma_f32_16x16x32_bf16(A[4], Bf[nf * 2 + 1], acc[0][nf], 0, 0, 0);
      acc[1][nf] = __builtin_amdgcn_mfma_f32_16x16x32_bf16(A[5], Bf[nf * 2 + 1], acc[1][nf], 0, 0, 0);
      acc[2][nf] = __builtin_amdgcn_mfma_f32_16x16x32_bf16(A[0], Bf[nf * 2 + 1], acc[2][nf], 0, 0, 0);
      acc[3][nf] = __builtin_amdgcn_mfma_f32_16x16x32_bf16(A[1], Bf[nf * 2 + 1], acc[3][nf], 0, 0, 0);
    }
    __builtin_amdgcn_s_setprio(0);
  }

  #pragma unroll
  for (int mf = 0; mf < 4; ++mf)
    #pragma unroll
    for (int nf = 0; nf < 4; ++nf)
      #pragma unroll
      for (int j2 = 0; j2 < 4; ++j2) {
        int s = s0 + wr * 64 + mf * 16 + kg * 4 + j2;
        int q = q0 + wc * 64 + nf * 16 + lm;
        mx[(size_t)(b * S_LEN + s) * KTOT + q] = f2bf(acc[mf][nf][j2]);
      }
}

// K3: h = relu(mx @ W_h + b_h); h_n extra write for s==4095 rows. (unchanged)
__global__ __launch_bounds__(256, 2) void k_gemm2(const short* __restrict__ mx,
                                                  const short* __restrict__ wht,
                                                  const float* __restrict__ bh,
                                                  float* __restrict__ out) {
  __shared__ __attribute__((aligned(16))) short At[4][128 * 64];

  int idx = blockIdx.x;
  int nt = idx & 1;
  int rt = idx >> 1;
  int R0 = rt << 7;

  int tid = threadIdx.x;
  int lane = tid & 63, wid = tid >> 6;
  int wr = wid >> 1, wc = wid & 1;
  int lm = lane & 15, kg = lane >> 4;
  int l3 = lane >> 3, l7 = lane & 7;
  int lm7 = lm & 7;

  const short* aSrc  = mx  + (size_t)(R0 + wid * 32 + l3) * KTOT + ((l7 ^ l3) << 3);
  const short* bBase = wht + (size_t)(nt * 128 + wc * 64 + lm) * KTOT + 8 * kg;

  int aRow = (wr * 64 + lm) * 64;
  int aof[8];
  #pragma unroll
  for (int f = 0; f < 4; ++f)
    #pragma unroll
    for (int ks = 0; ks < 2; ++ks)
      aof[f * 2 + ks] = aRow + f * 1024 + (((ks << 5) + (kg << 3)) ^ (lm7 << 3));

  f32x4 acc[4][4];
  #pragma unroll
  for (int ii = 0; ii < 4; ++ii)
    #pragma unroll
    for (int jn = 0; jn < 4; ++jn)
      acc[ii][jn] = (f32x4){0.0f, 0.0f, 0.0f, 0.0f};

  auto STAGE = [&](int cc) {
    int slot = cc & 3;
    #pragma unroll
    for (int ii = 0; ii < 4; ++ii)
      gload16(aSrc + (size_t)ii * 8 * KTOT + cc * 64, &At[slot][(wid * 32 + ii * 8) * 64]);
  };

  short8 Bcur[8], Bnxt[8];
  STAGE(0);
  STAGE(1);
  #pragma unroll
  for (int nf = 0; nf < 4; ++nf)
    #pragma unroll
    for (int ks = 0; ks < 2; ++ks)
      Bcur[nf * 2 + ks] = *(const short8*)(bBase + nf * 16 * KTOT + 32 * ks);

  for (int c = 0; c < 6; ++c) {
    if (c + 2 < 6) STAGE(c + 2);
    if (c + 1 < 6) {
      const short* bb = bBase + (c + 1) * 64;
      #pragma unroll
      for (int nf = 0; nf < 4; ++nf)
        #pragma unroll
        for (int ks = 0; ks < 2; ++ks)
          Bnxt[nf * 2 + ks] = *(const short8*)(bb + nf * 16 * KTOT + 32 * ks);
    }
    if (c + 2 < 6)      asm volatile("s_waitcnt vmcnt(12) lgkmcnt(0)\n\ts_barrier" ::: "memory");
    else if (c + 1 < 6) asm volatile("s_waitcnt vmcnt(8) lgkmcnt(0)\n\ts_barrier" ::: "memory");
    else                asm volatile("s_waitcnt vmcnt(0) lgkmcnt(0)\n\ts_barrier" ::: "memory");

    const short* AtB = &At[c & 3][0];
    short8 Af[8];
    #pragma unroll
    for (int ii = 0; ii < 8; ++ii) Af[ii] = *(const short8*)(AtB + aof[ii]);
    __builtin_amdgcn_s_setprio(1);
    #pragma unroll
    for (int ks = 0; ks < 2; ++ks)
      #pragma unroll
      for (int mf = 0; mf < 4; ++mf)
        #pragma unroll
        for (int nf = 0; nf < 4; ++nf)
          acc[mf][nf] = __builtin_amdgcn_mfma_f32_16x16x32_bf16(Af[mf * 2 + ks], Bcur[nf * 2 + ks], acc[mf][nf], 0, 0, 0);
    __builtin_amdgcn_s_setprio(0);
    #pragma unroll
    for (int ii = 0; ii < 8; ++ii) Bcur[ii] = Bnxt[ii];
  }

  #pragma unroll
  for (int mf = 0; mf < 4; ++mf)
    #pragma unroll
    for (int nf = 0; nf < 4; ++nf) {
      int n = nt * 128 + wc * 64 + nf * 16 + lm;
      float bias = bh[n];
      #pragma unroll
      for (int j = 0; j < 4; ++j) {
        int R = R0 + wr * 64 + mf * 16 + kg * 4 + j;
        float v = acc[mf][nf][j] + bias;
        v = v > 0.0f ? v : 0.0f;
        out[(size_t)R * 256 + n] = v;
        if ((R & (S_LEN - 1)) == (S_LEN - 1))
          out[HN_OFF + (R >> 12) * 256 + n] = v;
      }
    }
}

extern "C" void kernel_launch(void* const* d_in, const int* in_sizes, int n_in,
                              void* d_out, int out_size, void* d_ws, size_t ws_size,
                              hipStream_t stream) {
  const float* x  = (const float*)d_in[0];
  const float* Wu = (const float*)d_in[1];
  const float* bu = (const float*)d_in[2];
  const float* Wh = (const float*)d_in[3];
  const float* bh = (const float*)d_in[4];
  const float* H  = (const float*)d_in[5];
  float* out = (float*)d_out;

  char* ws = (char*)d_ws;
  float* u   = (float*)ws;                         // 131072 B
  short* cp  = (short*)(ws + 131072);              // 557056 B
  short* Hb  = (short*)(ws + 688128);              // 2097152 B
  short* wht = (short*)(ws + 2785280);             // 196608 B
  short* mx  = (short*)(ws + 2981888);             // 25165824 B (end 28147712)
  float2* Wt   = (float2*)(ws + 28147712);         // 65536 B
  float2* fftU = (float2*)(ws + 28213248);         // 524288 B
  float2* fftH = (float2*)(ws + 28737536);         // 16777216 B
  short*  mcol = (short*)(ws + 45514752);          // 16777216 B (end 62291968)

  k_prep<<<12744, 256, 0, stream>>>(x, Wu, bu, H, Wh, mx, cp, Hb, wht, u);

  if (ws_size >= 62291968ULL) {
    k_twid<<<32,   256, 0, stream>>>(Wt);
    k_fft <<<264,  256, 0, stream>>>(H, u, Wt, fftH, fftU);
    k_ifft<<<2048, 256, 0, stream>>>(fftU, fftH, Wt, mcol);
    k_tr  <<<2048, 256, 0, stream>>>(mcol, mx);
  } else {
    k_conv<<<512, 256, 0, stream>>>(cp, Hb, mx);
  }
  k_gemm2<<<512, 256, 0, stream>>>(mx, wht, bh, out);
}

// Round 12
// 82.891 us; speedup vs baseline: 2.3622x; 2.3622x over previous
//
#include <hip/hip_runtime.h>

#define S_LEN 4096
#define B_SZ 8
#define KTOT 384            // M (256) + D (128)
#define CPROWS 544          // 8-elem rows per parity copy (zero-padded past 4096)
#define HN_OFF 8388608      // 8*4096*256

typedef __attribute__((ext_vector_type(8))) short short8;
typedef __attribute__((ext_vector_type(4))) short short4v;
typedef __attribute__((ext_vector_type(4))) float f32x4;

typedef const __attribute__((address_space(1))) unsigned int as1_u32;
typedef __attribute__((address_space(3))) unsigned int as3_u32;

__device__ __forceinline__ void gload16(const short* g, short* l) {
  __builtin_amdgcn_global_load_lds((as1_u32*)g, (as3_u32*)l, 16, 0, 0);
}

__device__ __forceinline__ short f2bf(float f) {
  union { float f; unsigned u; } v; v.f = f;
  unsigned r = v.u + 0x7FFFu + ((v.u >> 16) & 1u);
  return (short)(r >> 16);
}

// K1 fused prep (vectorized):
//  [0,8192):      u = relu(x@W_u+b_u) scattered into 8 parity copies cp;
//                 x -> bf16 pairs into mx[...,256:384]
//  [8192,8264):   zero e>=4096 tail of cp
//  [8264,9288):   H -> bf16 (float4 / short4)
//  [9288,9672):   W_h^T -> bf16
__global__ __launch_bounds__(256) void k_prep(const float* __restrict__ x,
                                              const float* __restrict__ Wu,
                                              const float* __restrict__ bu,
                                              const float* __restrict__ H,
                                              const float* __restrict__ Wh,
                                              short* __restrict__ mx,
                                              short* __restrict__ cp,
                                              short* __restrict__ Hb,
                                              short* __restrict__ wht) {
  int bx = blockIdx.x;
  if (bx >= 9288) {
    int j = (bx - 9288) * 256 + threadIdx.x;
    if (j < 256 * KTOT) {
      int n = j / KTOT, k = j % KTOT;
      wht[j] = f2bf(Wh[k * 256 + n]);
    }
    return;
  }
  if (bx >= 8264) {
    int i4 = (bx - 8264) * 1024 + threadIdx.x * 4;
    float4 hv = *(const float4*)(H + i4);
    short4v o;
    o[0] = f2bf(hv.x); o[1] = f2bf(hv.y); o[2] = f2bf(hv.z); o[3] = f2bf(hv.w);
    *(short4v*)(Hb + i4) = o;
    return;
  }
  if (bx >= 8192) {
    int idx = (bx - 8192) * 256 + threadIdx.x;   // b(8)*p(8)*r(36)*j(8)
    if (idx < 18432) {
      int j = idx & 7;
      int r = 508 + ((idx >> 3) % 36);
      int rem = (idx >> 3) / 36;
      int p = rem & 7;
      int b = rem >> 3;
      int e = 8 * r + p + j;
      if (e >= S_LEN)
        cp[((size_t)(b * 8 + p) * CPROWS + r) * 8 + j] = 0;
    }
    return;
  }
  int row = bx * 4 + (threadIdx.x >> 6);   // b*4096 + t
  int l = threadIdx.x & 63;
  float2 xv = *(const float2*)(x + (size_t)row * 128 + 2 * l);
  float2 wv = *(const float2*)(Wu + 2 * l);
  float s = xv.x * wv.x + xv.y * wv.y;
  #pragma unroll
  for (int m = 32; m >= 1; m >>= 1) s += __shfl_xor(s, m, 64);
  unsigned pack = (((unsigned)f2bf(xv.y) & 0xFFFFu) << 16) | ((unsigned)f2bf(xv.x) & 0xFFFFu);
  *(unsigned*)(mx + (size_t)row * KTOT + 256 + 2 * l) = pack;
  float v = s + bu[0];
  v = v > 0.0f ? v : 0.0f;
  short vb = f2bf(v);
  if (l < 8) {
    int t = row & (S_LEN - 1);
    int b = row >> 12;
    int e = (S_LEN - 1) - t;       // u_rev index of this element
    int p = l;
    if (e >= p) {
      int d = e - p;
      cp[((size_t)(b * 8 + p) * CPROWS + (d >> 3)) * 8 + (d & 7)] = vb;
    }
  }
}

// K2: Toeplitz GEMM, BK=128. 128x128 tile, 4 waves, wave tile 64x64.
// Ring-2 LDS (B 2x32KB + A 2x4KB = 72KB -> 2 blocks/CU), ONE barrier/chunk:
// STAGE(c+1) issued right after the barrier; its writes target slot (c-1)&1
// whose readers finished before this barrier (lgkmcnt(0) drained). vmcnt(0)
// at chunk top is free: stage(c) was issued ~2000cy earlier (latency ~600).
// Per-chunk overhead (barrier+drain) amortized 2x vs BK=64 -> the one lever
// left after R2-R10 showed ~1900cy/BK64-chunk invariant.
// A window: BK=128 still fits 4KB/slot (span 128(k)+103(s)+24 = 255 units).
// R10 packing-robust balance map: co-resident pair = 33 chunks total.
__global__ __launch_bounds__(256, 2) void k_conv(const short* __restrict__ cp,
                                                 const short* __restrict__ Hb,
                                                 short* __restrict__ mx) {
  __shared__ __attribute__((aligned(16))) short Bt[2][128 * 128];  // 64 KB
  __shared__ __attribute__((aligned(16))) short Aw[2][2048];       // 8 KB

  int i = blockIdx.x;                 // 512 blocks, balance map
  int j  = i >> 1, lo = i & 1;
  int jj = j & 127;
  int fj = (j >> 7) ? (31 - (jj >> 3)) : (jj >> 3);
  int st = lo ? (31 - fj) : fj;
  int qt = lo;
  int b  = j & 7;
  int s0 = st << 7, q0 = qt << 7;

  int tid = threadIdx.x;
  int lane = tid & 63, wid = tid >> 6;
  int wr = wid >> 1, wc = wid & 1;      // wave tile 64(s) x 64(q)
  int lm = lane & 15, kg = lane >> 4;
  int l3 = lane >> 3, l7 = lane & 7;
  int lm7 = lm & 7;

  // B staging: rows of 128 tau (16 chunks of 16B), XOR-swizzled by row&7 via
  // pre-swizzled source chunk; linear LDS dest. Instr e covers 4 rows.
  const short* bS0 = Hb + (size_t)(q0 + wid * 32 + kg) * S_LEN + ((lm ^ kg) << 3);
  const short* bS1 = Hb + (size_t)(q0 + wid * 32 + kg) * S_LEN + ((lm ^ kg ^ 4) << 3);

  // A staging: parity pre-permuted (l7^l3); rows advance 16/chunk (128 elems)
  int asbase = 496 - 16 * st;
  const short* aSrc = cp + ((size_t)(b * 8 + (l7 ^ l3)) * CPROWS + asbase + wid * 8 + l3) * 8;

  // A-frag swizzled offsets: frag(mf,ks) -> v = 2*ks - mf + 3 in [0,10);
  // data unit d = dbase + 16v - 48; phys = (d&~7)|((d&7)^((d>>3)&7)).
  int dbase = 127 - 64 * wr - lm + 8 * kg;
  int aof[10];
  #pragma unroll
  for (int v = 0; v < 10; ++v) {
    int d = dbase + 16 * v - 48;
    aof[v] = ((d & ~7) | ((d & 7) ^ ((d >> 3) & 7))) << 3;   // shorts
  }

  // B-frag offsets: row wc*64+nf*16+lm, data chunk 4ks+kg, key lm&7
  int bof[16];
  #pragma unroll
  for (int nf = 0; nf < 4; ++nf)
    #pragma unroll
    for (int ks = 0; ks < 4; ++ks)
      bof[nf * 4 + ks] = (wc * 64 + nf * 16 + lm) * 128 + (((4 * ks + kg) ^ lm7) << 3);

  f32x4 acc[4][4];
  #pragma unroll
  for (int ii = 0; ii < 4; ++ii)
    #pragma unroll
    for (int jn = 0; jn < 4; ++jn)
      acc[ii][jn] = (f32x4){0.0f, 0.0f, 0.0f, 0.0f};

  int nchunks = st + 1;

  auto STAGE = [&](int cc) {
    int slot = cc & 1;
    int coff = cc * 128;
    #pragma unroll
    for (int e = 0; e < 4; ++e) {
      gload16(bS0 + (size_t)(8 * e) * S_LEN + coff,     &Bt[slot][(wid * 32 + 8 * e) * 128]);
      gload16(bS1 + (size_t)(8 * e + 4) * S_LEN + coff, &Bt[slot][(wid * 32 + 8 * e + 4) * 128]);
    }
    gload16(aSrc + coff, &Aw[slot][wid * 512]);
  };

  STAGE(0);

  for (int c = 0; c < nchunks; ++c) {
    asm volatile("s_waitcnt vmcnt(0) lgkmcnt(0)\n\ts_barrier" ::: "memory");
    if (c + 1 < nchunks) STAGE(c + 1);
    const short* AwB = &Aw[c & 1][0];
    const short* BtB = &Bt[c & 1][0];
    short8 A10[10];
    #pragma unroll
    for (int v = 0; v < 10; ++v) A10[v] = *(const short8*)(AwB + aof[v]);
    short8 Bf[16];
    #pragma unroll
    for (int ii = 0; ii < 16; ++ii) Bf[ii] = *(const short8*)(BtB + bof[ii]);
    __builtin_amdgcn_s_setprio(1);
    #pragma unroll
    for (int ks = 0; ks < 4; ++ks)
      #pragma unroll
      for (int mf = 0; mf < 4; ++mf)
        #pragma unroll
        for (int nf = 0; nf < 4; ++nf)
          acc[mf][nf] = __builtin_amdgcn_mfma_f32_16x16x32_bf16(
              A10[2 * ks - mf + 3], Bf[nf * 4 + ks], acc[mf][nf], 0, 0, 0);
    __builtin_amdgcn_s_setprio(0);
  }

  // C/D layout: col = lane&15, row = (lane>>4)*4 + reg
  #pragma unroll
  for (int mf = 0; mf < 4; ++mf)
    #pragma unroll
    for (int nf = 0; nf < 4; ++nf)
      #pragma unroll
      for (int j2 = 0; j2 < 4; ++j2) {
        int s = s0 + wr * 64 + mf * 16 + kg * 4 + j2;
        int q = q0 + wc * 64 + nf * 16 + lm;
        mx[(size_t)(b * S_LEN + s) * KTOT + q] = f2bf(acc[mf][nf][j2]);
      }
}

// K3: h = relu(mx @ W_h + b_h); h_n extra write for s==4095 rows. (R10)
__global__ __launch_bounds__(256, 2) void k_gemm2(const short* __restrict__ mx,
                                                  const short* __restrict__ wht,
                                                  const float* __restrict__ bh,
                                                  float* __restrict__ out) {
  __shared__ __attribute__((aligned(16))) short At[4][128 * 64];  // 64 KB

  int idx = blockIdx.x;       // 512 = 256 row-tiles * 2 n-tiles
  int nt = idx & 1;
  int rt = idx >> 1;
  int R0 = rt << 7;

  int tid = threadIdx.x;
  int lane = tid & 63, wid = tid >> 6;
  int wr = wid >> 1, wc = wid & 1;
  int lm = lane & 15, kg = lane >> 4;
  int l3 = lane >> 3, l7 = lane & 7;
  int lm7 = lm & 7;

  const short* aSrc  = mx  + (size_t)(R0 + wid * 32 + l3) * KTOT + ((l7 ^ l3) << 3);
  const short* bBase = wht + (size_t)(nt * 128 + wc * 64 + lm) * KTOT + 8 * kg;

  int aRow = (wr * 64 + lm) * 64;
  int aof[8];
  #pragma unroll
  for (int f = 0; f < 4; ++f)
    #pragma unroll
    for (int ks = 0; ks < 2; ++ks)
      aof[f * 2 + ks] = aRow + f * 1024 + (((ks << 5) + (kg << 3)) ^ (lm7 << 3));

  f32x4 acc[4][4];
  #pragma unroll
  for (int ii = 0; ii < 4; ++ii)
    #pragma unroll
    for (int jn = 0; jn < 4; ++jn)
      acc[ii][jn] = (f32x4){0.0f, 0.0f, 0.0f, 0.0f};

  auto STAGE = [&](int cc) {
    int slot = cc & 3;
    #pragma unroll
    for (int ii = 0; ii < 4; ++ii)
      gload16(aSrc + (size_t)ii * 8 * KTOT + cc * 64, &At[slot][(wid * 32 + ii * 8) * 64]);
  };

  short8 Bcur[8], Bnxt[8];
  STAGE(0);
  STAGE(1);
  #pragma unroll
  for (int nf = 0; nf < 4; ++nf)
    #pragma unroll
    for (int ks = 0; ks < 2; ++ks)
      Bcur[nf * 2 + ks] = *(const short8*)(bBase + nf * 16 * KTOT + 32 * ks);

  for (int c = 0; c < 6; ++c) {
    if (c + 2 < 6) STAGE(c + 2);
    if (c + 1 < 6) {
      const short* bb = bBase + (c + 1) * 64;
      #pragma unroll
      for (int nf = 0; nf < 4; ++nf)
        #pragma unroll
        for (int ks = 0; ks < 2; ++ks)
          Bnxt[nf * 2 + ks] = *(const short8*)(bb + nf * 16 * KTOT + 32 * ks);
    }
    if (c + 2 < 6)      asm volatile("s_waitcnt vmcnt(12) lgkmcnt(0)\n\ts_barrier" ::: "memory");
    else if (c + 1 < 6) asm volatile("s_waitcnt vmcnt(8) lgkmcnt(0)\n\ts_barrier" ::: "memory");
    else                asm volatile("s_waitcnt vmcnt(0) lgkmcnt(0)\n\ts_barrier" ::: "memory");

    const short* AtB = &At[c & 3][0];
    short8 Af[8];
    #pragma unroll
    for (int ii = 0; ii < 8; ++ii) Af[ii] = *(const short8*)(AtB + aof[ii]);
    __builtin_amdgcn_s_setprio(1);
    #pragma unroll
    for (int ks = 0; ks < 2; ++ks)
      #pragma unroll
      for (int mf = 0; mf < 4; ++mf)
        #pragma unroll
        for (int nf = 0; nf < 4; ++nf)
          acc[mf][nf] = __builtin_amdgcn_mfma_f32_16x16x32_bf16(Af[mf * 2 + ks], Bcur[nf * 2 + ks], acc[mf][nf], 0, 0, 0);
    __builtin_amdgcn_s_setprio(0);
    #pragma unroll
    for (int ii = 0; ii < 8; ++ii) Bcur[ii] = Bnxt[ii];
  }

  #pragma unroll
  for (int mf = 0; mf < 4; ++mf)
    #pragma unroll
    for (int nf = 0; nf < 4; ++nf) {
      int n = nt * 128 + wc * 64 + nf * 16 + lm;
      float bias = bh[n];
      #pragma unroll
      for (int j = 0; j < 4; ++j) {
        int R = R0 + wr * 64 + mf * 16 + kg * 4 + j;
        float v = acc[mf][nf][j] + bias;
        v = v > 0.0f ? v : 0.0f;
        out[(size_t)R * 256 + n] = v;
        if ((R & (S_LEN - 1)) == (S_LEN - 1))
          out[HN_OFF + (R >> 12) * 256 + n] = v;
      }
    }
}

extern "C" void kernel_launch(void* const* d_in, const int* in_sizes, int n_in,
                              void* d_out, int out_size, void* d_ws, size_t ws_size,
                              hipStream_t stream) {
  const float* x  = (const float*)d_in[0];
  const float* Wu = (const float*)d_in[1];
  const float* bu = (const float*)d_in[2];
  const float* Wh = (const float*)d_in[3];
  const float* bh = (const float*)d_in[4];
  const float* H  = (const float*)d_in[5];
  float* out = (float*)d_out;

  char* ws = (char*)d_ws;
  short* cp  = (short*)(ws + 131072);              // 557056 B
  short* Hb  = (short*)(ws + 688128);              // 2097152 B
  short* wht = (short*)(ws + 2785280);             // 196608 B
  short* mx  = (short*)(ws + 2981888);             // 25165824 B

  k_prep<<<9672, 256, 0, stream>>>(x, Wu, bu, H, Wh, mx, cp, Hb, wht);
  k_conv<<<512,  256, 0, stream>>>(cp, Hb, mx);
  k_gemm2<<<512, 256, 0, stream>>>(mx, wht, bh, out);
}

// Round 13
// 77.716 us; speedup vs baseline: 2.5195x; 1.0666x over previous
//
#include <hip/hip_runtime.h>

#define S_LEN 4096
#define B_SZ 8
#define HN_OFF 8388608      // 8*4096*256
#define CPROWS 544          // 8-elem rows per parity copy (zero-padded past 4096)

typedef __attribute__((ext_vector_type(8))) short short8;
typedef __attribute__((ext_vector_type(4))) float f32x4;

typedef const __attribute__((address_space(1))) unsigned int as1_u32;
typedef __attribute__((address_space(3))) unsigned int as3_u32;

__device__ __forceinline__ void gload16(const short* g, short* l) {
  __builtin_amdgcn_global_load_lds((as1_u32*)g, (as3_u32*)l, 16, 0, 0);
}

__device__ __forceinline__ short f2bf(float f) {
  union { float f; unsigned u; } v; v.f = f;
  unsigned r = v.u + 0x7FFFu + ((v.u >> 16) & 1u);
  return (short)(r >> 16);
}

// K1 fused prep:
//  [0,8192):      u = relu(x@W_u+b_u) -> 8 parity copies cp; x -> bf16 xb rows
//  [8192,8264):   zero e>=4096 tail of cp
//  [8264,8520):   H [256 q][4096 t] -> Ht bf16 [4096 t][256 q] (64x64 LDS transpose)
//  [8520,8904):   W_h^T -> bf16 wht[n*384+k] = Wh[k*256+n]
__global__ __launch_bounds__(256) void k_prep(const float* __restrict__ x,
                                              const float* __restrict__ Wu,
                                              const float* __restrict__ bu,
                                              const float* __restrict__ H,
                                              const float* __restrict__ Wh,
                                              short* __restrict__ cp,
                                              short* __restrict__ xb,
                                              short* __restrict__ Ht,
                                              short* __restrict__ wht) {
  int bx = blockIdx.x;
  if (bx >= 8520) {
    int j = (bx - 8520) * 256 + threadIdx.x;
    if (j < 256 * 384) {
      int n = j / 384, k = j % 384;
      wht[j] = f2bf(Wh[k * 256 + n]);
    }
    return;
  }
  if (bx >= 8264) {
    __shared__ short tile[64][72];
    int bx2 = bx - 8264;                 // 256 = tt(64) * qt(4)
    int t0 = (bx2 >> 2) << 6, q0 = (bx2 & 3) << 6;
    int tid = threadIdx.x;
    int r = tid >> 2, c0 = (tid & 3) << 4;
    const float* src = H + (size_t)(q0 + r) * S_LEN + t0 + c0;
    #pragma unroll
    for (int v4 = 0; v4 < 4; ++v4) {
      float4 hv = *(const float4*)(src + 4 * v4);
      tile[r][c0 + 4 * v4]     = f2bf(hv.x);
      tile[r][c0 + 4 * v4 + 1] = f2bf(hv.y);
      tile[r][c0 + 4 * v4 + 2] = f2bf(hv.z);
      tile[r][c0 + 4 * v4 + 3] = f2bf(hv.w);
    }
    __syncthreads();
    int s2 = tid >> 2, qc = (tid & 3) << 4;
    short8 o0, o1;
    #pragma unroll
    for (int j2 = 0; j2 < 8; ++j2) {
      o0[j2] = tile[qc + j2][s2];
      o1[j2] = tile[qc + 8 + j2][s2];
    }
    short* dst = Ht + (size_t)(t0 + s2) * 256 + q0 + qc;
    *(short8*)dst       = o0;
    *(short8*)(dst + 8) = o1;
    return;
  }
  if (bx >= 8192) {
    int idx = (bx - 8192) * 256 + threadIdx.x;   // b(8)*p(8)*r(36)*j(8)
    if (idx < 18432) {
      int j = idx & 7;
      int r = 508 + ((idx >> 3) % 36);
      int rem = (idx >> 3) / 36;
      int p = rem & 7;
      int b = rem >> 3;
      int e = 8 * r + p + j;
      if (e >= S_LEN)
        cp[((size_t)(b * 8 + p) * CPROWS + r) * 8 + j] = 0;
    }
    return;
  }
  int row = bx * 4 + (threadIdx.x >> 6);   // b*4096 + t
  int l = threadIdx.x & 63;
  float2 xv = *(const float2*)(x + (size_t)row * 128 + 2 * l);
  float2 wv = *(const float2*)(Wu + 2 * l);
  float s = xv.x * wv.x + xv.y * wv.y;
  #pragma unroll
  for (int m = 32; m >= 1; m >>= 1) s += __shfl_xor(s, m, 64);
  unsigned pack = (((unsigned)f2bf(xv.y) & 0xFFFFu) << 16) | ((unsigned)f2bf(xv.x) & 0xFFFFu);
  *(unsigned*)(xb + (size_t)row * 128 + 2 * l) = pack;
  float v = s + bu[0];
  v = v > 0.0f ? v : 0.0f;
  short vb = f2bf(v);
  if (l < 8) {
    int t = row & (S_LEN - 1);
    int b = row >> 12;
    int e = (S_LEN - 1) - t;       // u_rev index of this element
    int p = l;
    if (e >= p) {
      int d = e - p;
      cp[((size_t)(b * 8 + p) * CPROWS + (d >> 3)) * 8 + (d & 7)] = vb;
    }
  }
}

// K2: Gt[n][t] = sum_q Wh[q,n]*H[q,t]  (= H^T folded with W_h's m-part).
// 64 blocks = nt(2) x tt(32), 128x128 tile, K=256 (4 BK-64 chunks), register
// fragments from global (wht 192KB + Ht 2MB, L2-hot).
__global__ __launch_bounds__(256) void k_g(const short* __restrict__ wht,
                                           const short* __restrict__ Ht,
                                           short* __restrict__ Gt) {
  int nt = blockIdx.x & 1, tt = blockIdx.x >> 1;
  int n0 = nt << 7, t0 = tt << 7;
  int tid = threadIdx.x;
  int lane = tid & 63, wid = tid >> 6;
  int wr = wid >> 1, wc = wid & 1;
  int lm = lane & 15, kg = lane >> 4;

  const short* Abase = wht + (size_t)(n0 + wr * 64 + lm) * 384 + 8 * kg;
  const short* Bbase = Ht  + (size_t)(t0 + wc * 64 + lm) * 256 + 8 * kg;

  f32x4 acc[4][4];
  #pragma unroll
  for (int ii = 0; ii < 4; ++ii)
    #pragma unroll
    for (int jn = 0; jn < 4; ++jn)
      acc[ii][jn] = (f32x4){0.0f, 0.0f, 0.0f, 0.0f};

  #pragma unroll
  for (int c = 0; c < 4; ++c) {
    short8 a[8], bf[8];
    #pragma unroll
    for (int mf = 0; mf < 4; ++mf)
      #pragma unroll
      for (int ks = 0; ks < 2; ++ks)
        a[mf * 2 + ks] = *(const short8*)(Abase + mf * 16 * 384 + c * 64 + ks * 32);
    #pragma unroll
    for (int nf = 0; nf < 4; ++nf)
      #pragma unroll
      for (int ks = 0; ks < 2; ++ks)
        bf[nf * 2 + ks] = *(const short8*)(Bbase + nf * 16 * 256 + c * 64 + ks * 32);
    #pragma unroll
    for (int ks = 0; ks < 2; ++ks)
      #pragma unroll
      for (int mf = 0; mf < 4; ++mf)
        #pragma unroll
        for (int nf = 0; nf < 4; ++nf)
          acc[mf][nf] = __builtin_amdgcn_mfma_f32_16x16x32_bf16(a[mf * 2 + ks], bf[nf * 2 + ks], acc[mf][nf], 0, 0, 0);
  }

  #pragma unroll
  for (int mf = 0; mf < 4; ++mf)
    #pragma unroll
    for (int nf = 0; nf < 4; ++nf)
      #pragma unroll
      for (int j = 0; j < 4; ++j) {
        int n = n0 + wr * 64 + mf * 16 + kg * 4 + j;
        int t = t0 + wc * 64 + nf * 16 + lm;
        Gt[(size_t)n * S_LEN + t] = f2bf(acc[mf][nf][j]);
      }
}

// K3 fused: h[s,n] = relu( sum_tau u[s-tau]*Gt[n,tau] + sum_d x[s,d]*Whx[d,n] + bh[n] )
// R12 conv structure verbatim (BK=128, ring-2, 1 barrier/chunk, balance map),
// B-source Hb->Gt; one extra x-chunk (xb tile staged as A, Whx frags in regs);
// k_gemm2 epilogue (bias+relu+f32 out+h_n).
__global__ __launch_bounds__(256, 2) void k_fused(const short* __restrict__ cp,
                                                  const short* __restrict__ Gt,
                                                  const short* __restrict__ xb,
                                                  const short* __restrict__ wht,
                                                  const float* __restrict__ bh,
                                                  float* __restrict__ out) {
  __shared__ __attribute__((aligned(16))) short Bt[2][128 * 128];  // 64 KB
  __shared__ __attribute__((aligned(16))) short Aw[2][2048];       // 8 KB

  int i = blockIdx.x;                 // 512 blocks, balance map (R10-proven)
  int j  = i >> 1, lo = i & 1;
  int jj = j & 127;
  int fj = (j >> 7) ? (31 - (jj >> 3)) : (jj >> 3);
  int st = lo ? (31 - fj) : fj;
  int nt = lo;
  int b  = j & 7;
  int s0 = st << 7, n0 = nt << 7;

  int tid = threadIdx.x;
  int lane = tid & 63, wid = tid >> 6;
  int wr = wid >> 1, wc = wid & 1;      // wave tile 64(s) x 64(n)
  int lm = lane & 15, kg = lane >> 4;
  int l3 = lane >> 3, l7 = lane & 7;
  int lm7 = lm & 7;

  // B staging from Gt rows (n), 128-tau chunks, row-XOR swizzle via source.
  const short* bS0 = Gt + (size_t)(n0 + wid * 32 + kg) * S_LEN + ((lm ^ kg) << 3);
  const short* bS1 = Gt + (size_t)(n0 + wid * 32 + kg) * S_LEN + ((lm ^ kg ^ 4) << 3);

  // A (Toeplitz u) staging: parity pre-permuted (l7^l3)
  int asbase = 496 - 16 * st;
  const short* aSrc = cp + ((size_t)(b * 8 + (l7 ^ l3)) * CPROWS + asbase + wid * 8 + l3) * 8;

  // x staging (A-operand of the x-chunk), same tile shape, row stride 128
  const short* xS0 = xb + (size_t)(b * S_LEN + s0 + wid * 32 + kg) * 128 + ((lm ^ kg) << 3);
  const short* xS1 = xb + (size_t)(b * S_LEN + s0 + wid * 32 + kg) * 128 + ((lm ^ kg ^ 4) << 3);

  // A-frag (Toeplitz) swizzled offsets: v = 2*ks - mf + 3 in [0,10)
  int dbase = 127 - 64 * wr - lm + 8 * kg;
  int aof[10];
  #pragma unroll
  for (int v = 0; v < 10; ++v) {
    int d = dbase + 16 * v - 48;
    aof[v] = ((d & ~7) | ((d & 7) ^ ((d >> 3) & 7))) << 3;   // shorts
  }

  // B-frag offsets (rows n of Bt)
  int bof[16];
  #pragma unroll
  for (int nf = 0; nf < 4; ++nf)
    #pragma unroll
    for (int ks = 0; ks < 4; ++ks)
      bof[nf * 4 + ks] = (wc * 64 + nf * 16 + lm) * 128 + (((4 * ks + kg) ^ lm7) << 3);

  // x-chunk A-frag offsets (rows s of the staged x tile)
  int aofx[16];
  #pragma unroll
  for (int mf = 0; mf < 4; ++mf)
    #pragma unroll
    for (int ks = 0; ks < 4; ++ks)
      aofx[mf * 4 + ks] = (wr * 64 + mf * 16 + lm) * 128 + (((4 * ks + kg) ^ lm7) << 3);

  f32x4 acc[4][4];
  #pragma unroll
  for (int ii = 0; ii < 4; ++ii)
    #pragma unroll
    for (int jn = 0; jn < 4; ++jn)
      acc[ii][jn] = (f32x4){0.0f, 0.0f, 0.0f, 0.0f};

  int nchunks = st + 1;               // Toeplitz chunks; +1 x-chunk after

  auto STAGE = [&](int cc) {          // Toeplitz chunk staging
    int slot = cc & 1;
    int coff = cc * 128;
    #pragma unroll
    for (int e = 0; e < 4; ++e) {
      gload16(bS0 + (size_t)(8 * e) * S_LEN + coff,     &Bt[slot][(wid * 32 + 8 * e) * 128]);
      gload16(bS1 + (size_t)(8 * e + 4) * S_LEN + coff, &Bt[slot][(wid * 32 + 8 * e + 4) * 128]);
    }
    gload16(aSrc + coff, &Aw[slot][wid * 512]);
  };
  auto STAGE_X = [&]() {              // x tile into slot (st+1)&1
    int slot = (st + 1) & 1;
    #pragma unroll
    for (int e = 0; e < 4; ++e) {
      gload16(xS0 + (size_t)(8 * e) * 128,     &Bt[slot][(wid * 32 + 8 * e) * 128]);
      gload16(xS1 + (size_t)(8 * e + 4) * 128, &Bt[slot][(wid * 32 + 8 * e + 4) * 128]);
    }
  };

  STAGE(0);

  for (int c = 0; c < nchunks; ++c) {
    asm volatile("s_waitcnt vmcnt(0) lgkmcnt(0)\n\ts_barrier" ::: "memory");
    if (c + 1 < nchunks) STAGE(c + 1);
    else STAGE_X();
    const short* AwB = &Aw[c & 1][0];
    const short* BtB = &Bt[c & 1][0];
    short8 A10[10];
    #pragma unroll
    for (int v = 0; v < 10; ++v) A10[v] = *(const short8*)(AwB + aof[v]);
    short8 Bf[16];
    #pragma unroll
    for (int ii = 0; ii < 16; ++ii) Bf[ii] = *(const short8*)(BtB + bof[ii]);
    __builtin_amdgcn_s_setprio(1);
    #pragma unroll
    for (int ks = 0; ks < 4; ++ks)
      #pragma unroll
      for (int mf = 0; mf < 4; ++mf)
        #pragma unroll
        for (int nf = 0; nf < 4; ++nf)
          acc[mf][nf] = __builtin_amdgcn_mfma_f32_16x16x32_bf16(
              A10[2 * ks - mf + 3], Bf[nf * 4 + ks], acc[mf][nf], 0, 0, 0);
    __builtin_amdgcn_s_setprio(0);
  }

  // x-chunk: B-frags (Whx) from global registers, A-frags from staged x tile
  short8 Bx[16];
  #pragma unroll
  for (int nf = 0; nf < 4; ++nf)
    #pragma unroll
    for (int ks = 0; ks < 4; ++ks)
      Bx[nf * 4 + ks] = *(const short8*)(wht + (size_t)(n0 + wc * 64 + nf * 16 + lm) * 384 + 256 + 32 * ks + 8 * kg);
  asm volatile("s_waitcnt vmcnt(0) lgkmcnt(0)\n\ts_barrier" ::: "memory");
  {
    const short* XtB = &Bt[(st + 1) & 1][0];
    short8 Ax[16];
    #pragma unroll
    for (int ii = 0; ii < 16; ++ii) Ax[ii] = *(const short8*)(XtB + aofx[ii]);
    __builtin_amdgcn_s_setprio(1);
    #pragma unroll
    for (int ks = 0; ks < 4; ++ks)
      #pragma unroll
      for (int mf = 0; mf < 4; ++mf)
        #pragma unroll
        for (int nf = 0; nf < 4; ++nf)
          acc[mf][nf] = __builtin_amdgcn_mfma_f32_16x16x32_bf16(
              Ax[mf * 4 + ks], Bx[nf * 4 + ks], acc[mf][nf], 0, 0, 0);
    __builtin_amdgcn_s_setprio(0);
  }

  // Epilogue: bias + relu + f32 store (+ h_n for s==4095)
  #pragma unroll
  for (int mf = 0; mf < 4; ++mf)
    #pragma unroll
    for (int nf = 0; nf < 4; ++nf) {
      int n = n0 + wc * 64 + nf * 16 + lm;
      float bias = bh[n];
      #pragma unroll
      for (int j2 = 0; j2 < 4; ++j2) {
        int s = s0 + wr * 64 + mf * 16 + kg * 4 + j2;
        float v = acc[mf][nf][j2] + bias;
        v = v > 0.0f ? v : 0.0f;
        out[(size_t)(b * S_LEN + s) * 256 + n] = v;
        if (s == S_LEN - 1)
          out[HN_OFF + b * 256 + n] = v;
      }
    }
}

extern "C" void kernel_launch(void* const* d_in, const int* in_sizes, int n_in,
                              void* d_out, int out_size, void* d_ws, size_t ws_size,
                              hipStream_t stream) {
  const float* x  = (const float*)d_in[0];
  const float* Wu = (const float*)d_in[1];
  const float* bu = (const float*)d_in[2];
  const float* Wh = (const float*)d_in[3];
  const float* bh = (const float*)d_in[4];
  const float* H  = (const float*)d_in[5];
  float* out = (float*)d_out;

  char* ws = (char*)d_ws;
  short* cp  = (short*)(ws);                       // 557056 B
  short* wht = (short*)(ws + 557056);              // 196608 B
  short* xb  = (short*)(ws + 753664);              // 8388608 B
  short* Ht  = (short*)(ws + 9142272);             // 2097152 B
  short* Gt  = (short*)(ws + 11239424);            // 2097152 B (end 13336576)

  k_prep<<<8904, 256, 0, stream>>>(x, Wu, bu, H, Wh, cp, xb, Ht, wht);
  k_g   <<<64,   256, 0, stream>>>(wht, Ht, Gt);
  k_fused<<<512, 256, 0, stream>>>(cp, Gt, xb, wht, bh, out);
}